// Round 1
// baseline (82.119 us; speedup 1.0000x reference)
//
#include <hip/hip_runtime.h>

// ProtoLayer: out[t][q][w] = -sum_c (query[t][q][c] - mean_s support[t][w*S+s][c])^2
// T=4, WAY=16, SHOT=8, QUERY=256 (=> 4096 queries/t), C=256. fp32 in/out.
// support_target is unused by the reference (prototype = reshape-mean).

constexpr int T_    = 4;
constexpr int WAY   = 16;
constexpr int SHOT  = 8;
constexpr int QUERY = 256;
constexpr int C     = 256;
constexpr int WQ    = WAY * QUERY;     // 4096 queries per t
constexpr int QT    = 32;              // queries per block
constexpr int NTHR  = 128;             // 2 waves
constexpr int PAD   = C + 4;           // LDS row pitch: bank-quad stride 4 -> worst 2-way (free)

__global__ __launch_bounds__(NTHR) void proto_dist_kernel(
    const float* __restrict__ query,    // (T, WQ, C)
    const float* __restrict__ support,  // (T, WAY*SHOT, C)
    float* __restrict__ out)            // (T, WQ, WAY)
{
    __shared__ float ps[WAY][PAD];      // prototypes
    __shared__ float qs[QT][PAD];       // query tile

    const int tid = threadIdx.x;
    constexpr int BLOCKS_PER_T = WQ / QT;   // 128
    const int t  = blockIdx.x / BLOCKS_PER_T;
    const int qb = (blockIdx.x % BLOCKS_PER_T) * QT;

    // ---- Phase 1: prototypes (channel-per-lane, coalesced; support L2-resident) ----
    const float* sup_t = support + (size_t)t * (WAY * SHOT * C);
    for (int c = tid; c < C; c += NTHR) {
        #pragma unroll
        for (int w = 0; w < WAY; ++w) {
            float s = 0.f;
            const float* sw = sup_t + (w * SHOT) * C + c;
            #pragma unroll
            for (int sh = 0; sh < SHOT; ++sh) s += sw[sh * C];
            ps[w][c] = s * (1.0f / SHOT);
        }
    }

    // ---- Phase 2: stage query tile, coalesced float4 ----
    const float4* qsrc = (const float4*)(query + ((size_t)t * WQ + qb) * C);
    #pragma unroll
    for (int i = 0; i < (QT * C / 4) / NTHR; ++i) {   // 16 iters
        int idx = tid + i * NTHR;                     // float4 index in tile
        int q   = idx / (C / 4);
        int c4  = (idx % (C / 4)) * 4;
        float4 v = qsrc[idx];
        float* dst = &qs[q][c4];
        dst[0] = v.x; dst[1] = v.y; dst[2] = v.z; dst[3] = v.w;
    }
    __syncthreads();

    // ---- Phase 3: thread -> (query q = tid>>2, ways [wg, wg+4)) ----
    const int q  = tid >> 2;
    const int wg = (tid & 3) * 4;
    float acc[4] = {0.f, 0.f, 0.f, 0.f};
    #pragma unroll 4
    for (int c = 0; c < C; c += 4) {
        float4 qv = *(const float4*)&qs[q][c];        // 4-lane broadcast, ~free
        #pragma unroll
        for (int j = 0; j < 4; ++j) {
            float4 pv = *(const float4*)&ps[wg + j][c];  // 16-lane broadcast
            float d0 = qv.x - pv.x;
            float d1 = qv.y - pv.y;
            float d2 = qv.z - pv.z;
            float d3 = qv.w - pv.w;
            acc[j] += d0 * d0 + d1 * d1 + d2 * d2 + d3 * d3;
        }
    }

    // ---- Phase 4: one coalesced float4 store per thread ----
    float4 r;
    r.x = -acc[0]; r.y = -acc[1]; r.z = -acc[2]; r.w = -acc[3];
    float4* dst = (float4*)(out + (((size_t)t * WQ + qb + q) * WAY + wg));
    *dst = r;
}

extern "C" void kernel_launch(void* const* d_in, const int* in_sizes, int n_in,
                              void* d_out, int out_size, void* d_ws, size_t ws_size,
                              hipStream_t stream) {
    const float* query   = (const float*)d_in[0];
    const float* support = (const float*)d_in[1];
    // d_in[2] (support_target) and the scalar way/shot/query counts are unused:
    // the reference ignores the labels and the shape constants are compile-time.
    float* out = (float*)d_out;

    dim3 grid(T_ * (WQ / QT));   // 512 blocks
    proto_dist_kernel<<<grid, NTHR, 0, stream>>>(query, support, out);
}

// Round 2
// 79.043 us; speedup vs baseline: 1.0389x; 1.0389x over previous
//
#include <hip/hip_runtime.h>

// ProtoLayer: out[t][q][w] = -sum_c (query[t][q][c] - mean_s support[t][w*S+s][c])^2
// T=4, WAY=16, SHOT=8, QUERY=256 (=> 4096 queries/t), C=256. fp32 in/out.
// support_target is unused by the reference (prototype = reshape-mean).
//
// Two kernels:
//   1) proto_kernel: proto[t][w][c] = mean over shots  -> d_ws (64 KB), computed ONCE
//      (round-1 version recomputed all 16 protos in every one of 512 blocks).
//   2) dist_kernel: 512 blocks x 128 thr; thread = 2 queries x 2 ways register tile
//      -> 4 ds_read_b128 per c4-step (vs 5 for 1qx4w), DS-pipe floor ~5 us.
//      LDS pitch 260 floats => broadcast reads are 2-way bank aliased (free, m136).

constexpr int T_    = 4;
constexpr int WAY   = 16;
constexpr int SHOT  = 8;
constexpr int C     = 256;
constexpr int WQ    = 4096;            // WAY*QUERY queries per t
constexpr int C4    = C / 4;           // 64 float4 per row
constexpr int PITCH = 260;             // LDS row pitch in floats

// ---------------- Kernel 1: prototypes ----------------
// grid = 16 blocks (t*4 + quarter), 256 threads; each thread one float4 output.
__global__ __launch_bounds__(256) void proto_kernel(
    const float* __restrict__ support,   // (T, WAY*SHOT, C)
    float* __restrict__ proto)           // (T, WAY, C) in d_ws
{
    const int t       = blockIdx.x >> 2;
    const int quarter = blockIdx.x & 3;
    const int idx     = quarter * 256 + threadIdx.x;   // [0, WAY*C4) = [0,1024)
    const int w  = idx >> 6;                            // [0,16)
    const int c4 = idx & 63;                            // [0,64)

    const float4* row = (const float4*)(support + (size_t)t * (WAY * SHOT * C))
                        + (w * SHOT) * C4 + c4;
    float4 s = make_float4(0.f, 0.f, 0.f, 0.f);
    #pragma unroll
    for (int sh = 0; sh < SHOT; ++sh) {
        float4 v = row[sh * C4];
        s.x += v.x; s.y += v.y; s.z += v.z; s.w += v.w;
    }
    s.x *= 0.125f; s.y *= 0.125f; s.z *= 0.125f; s.w *= 0.125f;

    float4* dst = (float4*)(proto + (size_t)t * (WAY * C));
    dst[w * C4 + c4] = s;
}

// ---------------- Kernel 2: distances ----------------
// grid = 512 blocks (t*128 + qtile), 128 threads (2 waves).
// Block covers 32 queries x 16 ways. Thread = queries {2ql,2ql+1} x ways {wg,wg+1}.
__global__ __launch_bounds__(128) void dist_kernel(
    const float* __restrict__ query,    // (T, WQ, C)
    const float* __restrict__ proto,    // (T, WAY, C)
    float* __restrict__ out)            // (T, WQ, WAY)
{
    __shared__ float ps[WAY * PITCH];   // 16.6 KB
    __shared__ float qs[32  * PITCH];   // 33.3 KB   (total ~50 KB -> 3 blocks/CU cap)

    const int tid = threadIdx.x;
    const int t   = blockIdx.x >> 7;            // 128 blocks per t
    const int qb  = (blockIdx.x & 127) * 32;

    // stage protos: 1024 float4 / 128 thr = 8 each, coalesced
    {
        const float4* src = (const float4*)(proto + (size_t)t * (WAY * C));
        #pragma unroll
        for (int i = 0; i < 8; ++i) {
            int idx = tid + i * 128;            // [0,1024)
            int w = idx >> 6, c4 = idx & 63;
            float4 v = src[idx];
            *(float4*)&ps[w * PITCH + c4 * 4] = v;
        }
    }
    // stage query tile: 32 rows x 64 float4 = 2048 / 128 thr = 16 each, coalesced
    {
        const float4* src = (const float4*)(query + ((size_t)t * WQ + qb) * C);
        #pragma unroll
        for (int i = 0; i < 16; ++i) {
            int idx = tid + i * 128;            // [0,2048)
            int q = idx >> 6, c4 = idx & 63;
            float4 v = src[idx];
            *(float4*)&qs[q * PITCH + c4 * 4] = v;
        }
    }
    __syncthreads();

    const int ql = tid >> 3;            // [0,16): queries 2ql, 2ql+1 (block-local)
    const int wg = (tid & 7) * 2;       // ways wg, wg+1

    const float* q0 = &qs[(2 * ql + 0) * PITCH];
    const float* q1 = &qs[(2 * ql + 1) * PITCH];
    const float* p0 = &ps[(wg + 0) * PITCH];
    const float* p1 = &ps[(wg + 1) * PITCH];

    float a00 = 0.f, a01 = 0.f, a10 = 0.f, a11 = 0.f;
    #pragma unroll 8
    for (int c = 0; c < C; c += 4) {
        float4 qa = *(const float4*)(q0 + c);
        float4 qv = *(const float4*)(q1 + c);
        float4 pa = *(const float4*)(p0 + c);
        float4 pb = *(const float4*)(p1 + c);

        float d;
        d = qa.x - pa.x; a00 += d * d;
        d = qa.y - pa.y; a00 += d * d;
        d = qa.z - pa.z; a00 += d * d;
        d = qa.w - pa.w; a00 += d * d;

        d = qa.x - pb.x; a01 += d * d;
        d = qa.y - pb.y; a01 += d * d;
        d = qa.z - pb.z; a01 += d * d;
        d = qa.w - pb.w; a01 += d * d;

        d = qv.x - pa.x; a10 += d * d;
        d = qv.y - pa.y; a10 += d * d;
        d = qv.z - pa.z; a10 += d * d;
        d = qv.w - pa.w; a10 += d * d;

        d = qv.x - pb.x; a11 += d * d;
        d = qv.y - pb.y; a11 += d * d;
        d = qv.z - pb.z; a11 += d * d;
        d = qv.w - pb.w; a11 += d * d;
    }

    // queries are consecutive, ways adjacent -> two float2 stores, 64B-chunk coalesced
    float* ob = out + (((size_t)t * WQ + qb + 2 * ql) * WAY + wg);
    *(float2*)ob         = make_float2(-a00, -a01);
    *(float2*)(ob + WAY) = make_float2(-a10, -a11);
}

extern "C" void kernel_launch(void* const* d_in, const int* in_sizes, int n_in,
                              void* d_out, int out_size, void* d_ws, size_t ws_size,
                              hipStream_t stream) {
    const float* query   = (const float*)d_in[0];
    const float* support = (const float*)d_in[1];
    // d_in[2] (support_target) unused: reference ignores labels (plain reshape-mean).
    float* out   = (float*)d_out;
    float* proto = (float*)d_ws;        // 4*16*256*4 = 64 KB scratch

    proto_kernel<<<dim3(T_ * 4), 256, 0, stream>>>(support, proto);
    dist_kernel <<<dim3(T_ * 128), 128, 0, stream>>>(query, proto, out);
}